// Round 1
// baseline (532.040 us; speedup 1.0000x reference)
//
#include <hip/hip_runtime.h>

#define DHW (64*128*128)

// accumulator layout in d_ws (floats)
#define OFF_NLL    0      // 1
#define OFF_CARDP  1      // [2][8]
#define OFF_INTER  17     // [2][8]
#define OFF_CARDG  33     // [2][8]
#define OFF_WSUM   49     // [2][17]
#define OFF_CNT    83     // [2][17]
#define OFF_CNUM   117    // [2][17][16]
#define OFF_CTR    661    // [2][17][16]
#define OFF_PULL   1205   // [2][17]
#define ACC_FLOATS 1239

__global__ void zero_kernel(float* acc) {
    int i = blockIdx.x * 1024 + threadIdx.x;
    if (i < ACC_FLOATS) acc[i] = 0.0f;
}

// ---------------- CE + Dice fused ----------------
__global__ __launch_bounds__(256) void ce_dice_kernel(const float* __restrict__ logits,
                                                      const int* __restrict__ cls,
                                                      float* __restrict__ acc) {
    int b = blockIdx.y;
    int tid = threadIdx.x;
    int vb = (blockIdx.x * 256 + tid) * 4;   // 4 consecutive voxels per thread
    const float* lg = logits + (size_t)b * 8 * DHW;
    const int* cl = cls + (size_t)b * DHW;

    float4 xc[8];
#pragma unroll
    for (int c = 0; c < 8; ++c)
        xc[c] = *reinterpret_cast<const float4*>(&lg[(size_t)c * DHW + vb]);
    int4 t4 = *reinterpret_cast<const int4*>(&cl[vb]);
    int tt[4] = {t4.x, t4.y, t4.z, t4.w};

    float nll = 0.f, cardp[8], inter[8], cardg[8];
#pragma unroll
    for (int c = 0; c < 8; ++c) { cardp[c] = 0.f; inter[c] = 0.f; cardg[c] = 0.f; }

#pragma unroll
    for (int j = 0; j < 4; ++j) {
        float x[8];
#pragma unroll
        for (int c = 0; c < 8; ++c) x[c] = ((const float*)&xc[c])[j];
        int t = tt[j];
        bool valid = (t != -100);
        float mx = x[0];
#pragma unroll
        for (int c = 1; c < 8; ++c) mx = fmaxf(mx, x[c]);
        float e[8], s = 0.f;
#pragma unroll
        for (int c = 0; c < 8; ++c) { e[c] = __expf(x[c] - mx); s += e[c]; }
        float inv = 1.0f / s;
        float lse = __logf(s);
        if (valid) {
#pragma unroll
            for (int c = 0; c < 8; ++c) {
                float p = e[c] * inv;
                cardp[c] += p;
                if (t == c) { inter[c] += p; cardg[c] += 1.f; nll += mx + lse - x[c]; }
            }
        }
    }

    // block reduce 25 values -> global atomics
    __shared__ float sh[25];
    if (tid < 25) sh[tid] = 0.f;
    __syncthreads();
    int lane = tid & 63;
    float vals[25];
    vals[0] = nll;
#pragma unroll
    for (int c = 0; c < 8; ++c) { vals[1 + c] = cardp[c]; vals[9 + c] = inter[c]; vals[17 + c] = cardg[c]; }
#pragma unroll
    for (int i = 0; i < 25; ++i) {
        float r = vals[i];
#pragma unroll
        for (int off = 32; off > 0; off >>= 1) r += __shfl_down(r, off, 64);
        if (lane == 0) atomicAdd(&sh[i], r);
    }
    __syncthreads();
    if (tid < 25) {
        int dst;
        if (tid == 0) dst = OFF_NLL;
        else if (tid < 9) dst = OFF_CARDP + b * 8 + (tid - 1);
        else if (tid < 17) dst = OFF_INTER + b * 8 + (tid - 9);
        else dst = OFF_CARDG + b * 8 + (tid - 17);
        atomicAdd(&acc[dst], sh[tid]);
    }
}

// boundary weight for 4 consecutive-in-x voxels (x multiple of 4)
__device__ inline void edge_w4(const int* __restrict__ L, int vb, const int c[4], float w[4]) {
    int x = vb & 127;
    int y = (vb >> 7) & 127;
    int z = vb >> 14;
    int z0 = max(z - 1, 0), z1 = min(z + 1, 63);
    int y0 = max(y - 1, 0), y1 = min(y + 1, 127);
    bool bnd0 = false, bnd1 = false, bnd2 = false, bnd3 = false;
    for (int zz = z0; zz <= z1; ++zz)
        for (int yy = y0; yy <= y1; ++yy) {
            const int* row = L + (zz << 14) + (yy << 7);
            int t[6];
#pragma unroll
            for (int d = 0; d < 6; ++d) {
                int xx = min(max(x - 1 + d, 0), 127);
                t[d] = row[xx];
            }
            bnd0 = bnd0 || (t[0] != c[0]) || (t[1] != c[0]) || (t[2] != c[0]);
            bnd1 = bnd1 || (t[1] != c[1]) || (t[2] != c[1]) || (t[3] != c[1]);
            bnd2 = bnd2 || (t[2] != c[2]) || (t[3] != c[2]) || (t[4] != c[2]);
            bnd3 = bnd3 || (t[3] != c[3]) || (t[4] != c[3]) || (t[5] != c[3]);
        }
    w[0] = bnd0 ? 10.f : 1.f;
    w[1] = bnd1 ? 10.f : 1.f;
    w[2] = bnd2 ? 10.f : 1.f;
    w[3] = bnd3 ? 10.f : 1.f;
}

// ---------------- pass 1: segment sums ----------------
__global__ __launch_bounds__(256) void segsum_kernel(const float* __restrict__ embed,
                                                     const int* __restrict__ labels,
                                                     float* __restrict__ acc) {
    int b = blockIdx.y;
    int tid = threadIdx.x;
    __shared__ float s[17 * 19];   // [k][stat] stride 19 (bank spread); stat: 0=w,1=cnt,2..17=cnum
    for (int i = tid; i < 17 * 19; i += 256) s[i] = 0.f;
    __syncthreads();

    const int* L = labels + (size_t)b * DHW;
    const float* E = embed + (size_t)b * 16 * DHW;
    int vb = (blockIdx.x * 256 + tid) * 4;

    int4 l4 = *reinterpret_cast<const int4*>(&L[vb]);
    int l[4] = {l4.x, l4.y, l4.z, l4.w};
    float w[4];
    edge_w4(L, vb, l, w);

    float4 e4[16];
#pragma unroll
    for (int c = 0; c < 16; ++c)
        e4[c] = *reinterpret_cast<const float4*>(&E[(size_t)c * DHW + vb]);

#pragma unroll
    for (int j = 0; j < 4; ++j) {
        if (l[j] != 0) {              // segment 0 never reaches the outputs
            float* row = &s[l[j] * 19];
            atomicAdd(&row[0], w[j]);
            atomicAdd(&row[1], 1.f);
#pragma unroll
            for (int c = 0; c < 16; ++c)
                atomicAdd(&row[2 + c], ((const float*)&e4[c])[j] * w[j]);
        }
    }
    __syncthreads();
    for (int i = tid; i < 17 * 19; i += 256) {
        int k = i / 19, st = i % 19;
        if (k == 0 || st >= 18) continue;
        float v = s[i];
        if (v != 0.f) {
            int dst;
            if (st == 0) dst = OFF_WSUM + b * 17 + k;
            else if (st == 1) dst = OFF_CNT + b * 17 + k;
            else dst = OFF_CNUM + (b * 17 + k) * 16 + (st - 2);
            atomicAdd(&acc[dst], v);
        }
    }
}

__global__ void centers_kernel(float* acc) {
    int i = blockIdx.x * 256 + threadIdx.x;
    if (i < 544) {
        int bk = i >> 4;  // b*17+k
        acc[OFF_CTR + i] = acc[OFF_CNUM + i] / (acc[OFF_WSUM + bk] + 1e-8f);
    }
}

// ---------------- pass 2: pull ----------------
__global__ __launch_bounds__(256) void pull_kernel(const float* __restrict__ embed,
                                                   const int* __restrict__ labels,
                                                   float* __restrict__ acc) {
    int b = blockIdx.y;
    int tid = threadIdx.x;
    __shared__ float ctr[17 * 17];  // stride 17 to spread banks
    __shared__ float ps[17];
    for (int i = tid; i < 17 * 17; i += 256) {
        int k = i / 17, c = i % 17;
        ctr[i] = (c < 16) ? acc[OFF_CTR + (b * 17 + k) * 16 + c] : 0.f;
    }
    if (tid < 17) ps[tid] = 0.f;
    __syncthreads();

    const int* L = labels + (size_t)b * DHW;
    const float* E = embed + (size_t)b * 16 * DHW;
    int vb = (blockIdx.x * 256 + tid) * 4;

    int4 l4 = *reinterpret_cast<const int4*>(&L[vb]);
    int l[4] = {l4.x, l4.y, l4.z, l4.w};
    float w[4];
    edge_w4(L, vb, l, w);

    float4 e4[16];
#pragma unroll
    for (int c = 0; c < 16; ++c)
        e4[c] = *reinterpret_cast<const float4*>(&E[(size_t)c * DHW + vb]);

#pragma unroll
    for (int j = 0; j < 4; ++j) {
        if (l[j] != 0) {
            const float* cg = &ctr[l[j] * 17];
            float d2 = 0.f;
#pragma unroll
            for (int c = 0; c < 16; ++c) {
                float dd = ((const float*)&e4[c])[j] - cg[c];
                d2 += dd * dd;
            }
            float d = fmaxf(sqrtf(d2) - 0.5f, 0.f);
            atomicAdd(&ps[l[j]], d * d * w[j]);
        }
    }
    __syncthreads();
    if (tid >= 1 && tid < 17) {
        float v = ps[tid];
        if (v != 0.f) atomicAdd(&acc[OFF_PULL + b * 17 + tid], v);
    }
}

// ---------------- finalize ----------------
__global__ void finalize_kernel(const float* __restrict__ acc, float* __restrict__ out) {
    __shared__ float sh_push[2], sh_norm[2], sh_pull[2], sh_npres[2];
    int tid = threadIdx.x;
    if (tid < 2) { sh_push[tid] = 0.f; sh_norm[tid] = 0.f; sh_pull[tid] = 0.f; sh_npres[tid] = 0.f; }
    __syncthreads();

    // per (b,k): present, npres, pull, norm  (32 tasks)
    if (tid < 32) {
        int b = tid >> 4, k = (tid & 15) + 1;
        float cnt = acc[OFF_CNT + b * 17 + k];
        if (cnt > 0.f) {
            atomicAdd(&sh_npres[b], 1.f);
            atomicAdd(&sh_pull[b], acc[OFF_PULL + b * 17 + k] / fmaxf(cnt, 1.f));
            const float* c = &acc[OFF_CTR + (b * 17 + k) * 16];
            float n2 = 0.f;
            for (int i = 0; i < 16; ++i) n2 += c[i] * c[i];
            atomicAdd(&sh_norm[b], sqrtf(n2));
        }
    }
    // pairs: 2 * 120 tasks
    for (int t = tid; t < 240; t += blockDim.x) {
        int b = t / 120, p = t % 120;
        int i = 1, rem = p;
        while (rem >= (16 - i)) { rem -= (16 - i); ++i; }
        int j = i + 1 + rem;
        bool pi = acc[OFF_CNT + b * 17 + i] > 0.f;
        bool pj = acc[OFF_CNT + b * 17 + j] > 0.f;
        if (pi && pj) {
            const float* ci = &acc[OFF_CTR + (b * 17 + i) * 16];
            const float* cj = &acc[OFF_CTR + (b * 17 + j) * 16];
            float d2 = 0.f;
            for (int c = 0; c < 16; ++c) { float dd = ci[c] - cj[c]; d2 += dd * dd; }
            float r = fmaxf(3.0f - sqrtf(d2), 0.f);   // 2*DELTA_D = 3.0
            atomicAdd(&sh_push[b], r * r);
        }
    }
    __syncthreads();
    if (tid == 0) {
        float nll = acc[OFF_NLL];
        float vcnt = 0.f;
        for (int i = 0; i < 16; ++i) vcnt += acc[OFF_CARDG + i];
        float ce = nll / fmaxf(vcnt, 1.f);
        float dsum = 0.f;
        for (int i = 0; i < 16; ++i) {
            float it = acc[OFF_INTER + i], cp = acc[OFF_CARDP + i], cg = acc[OFF_CARDG + i];
            dsum += (2.f * it + 1e-5f) / (cp + cg + 1e-5f);
        }
        float dice = 1.f - dsum / 16.f;
        float lp = 0.f, lpu = 0.f, ln = 0.f, val = 0.f;
        for (int b = 0; b < 2; ++b) {
            float npres = sh_npres[b];
            lp += sh_pull[b];
            float npairs = npres * (npres - 1.f) * 0.5f;
            lpu += (npairs > 0.f) ? sh_push[b] / fmaxf(npairs, 1.f) : 0.f;
            ln += (npres > 0.f) ? sh_norm[b] / fmaxf(npres, 1.f) : 0.f;
            val += (npres > 0.f) ? 1.f : 0.f;
        }
        float n = fmaxf(val, 1.f);
        float ins = (1.0f * lp + 1.0f * lpu + 0.001f * ln) / n;
        float sem = ce + dice;
        out[0] = sem + ins;
        out[1] = sem;
        out[2] = ce;
        out[3] = dice;
        out[4] = ins;
    }
}

extern "C" void kernel_launch(void* const* d_in, const int* in_sizes, int n_in,
                              void* d_out, int out_size, void* d_ws, size_t ws_size,
                              hipStream_t stream) {
    const float* sem = (const float*)d_in[0];
    const float* emb = (const float*)d_in[1];
    const int* cls = (const int*)d_in[2];
    const int* lab = (const int*)d_in[3];
    float* out = (float*)d_out;
    float* acc = (float*)d_ws;

    hipLaunchKernelGGL(zero_kernel, dim3(2), dim3(1024), 0, stream, acc);
    hipLaunchKernelGGL(ce_dice_kernel, dim3(1024, 2), dim3(256), 0, stream, sem, cls, acc);
    hipLaunchKernelGGL(segsum_kernel, dim3(1024, 2), dim3(256), 0, stream, emb, lab, acc);
    hipLaunchKernelGGL(centers_kernel, dim3(3), dim3(256), 0, stream, acc);
    hipLaunchKernelGGL(pull_kernel, dim3(1024, 2), dim3(256), 0, stream, emb, lab, acc);
    hipLaunchKernelGGL(finalize_kernel, dim3(1), dim3(256), 0, stream, acc, out);
}

// Round 2
// 393.006 us; speedup vs baseline: 1.3538x; 1.3538x over previous
//
#include <hip/hip_runtime.h>

#define DHW (64*128*128)

// accumulator layout in d_ws (floats)
#define OFF_NLL    0      // 1
#define OFF_CARDP  1      // [2][8]
#define OFF_INTER  17     // [2][8]
#define OFF_CARDG  33     // [2][8]
#define OFF_WSUM   49     // [2][17]
#define OFF_CNT    83     // [2][17]
#define OFF_CNUM   117    // [2][17][16]
#define OFF_CTR    661    // [2][17][16]
#define OFF_PULL   1205   // [2][17]
#define ACC_FLOATS 1239
#define BND_BYTE_OFF 8192   // u8 boundary mask [2][DHW] starts here in d_ws

typedef __bf16 bf16x8 __attribute__((ext_vector_type(8)));
typedef float f32x4 __attribute__((ext_vector_type(4)));
union FragU { short s[8]; bf16x8 v; };

__device__ inline short f2bf(float f) {   // RTNE float->bf16
    union { float f; unsigned u; } v; v.f = f;
    unsigned r = v.u + 0x7FFF + ((v.u >> 16) & 1);
    return (short)(r >> 16);
}

__global__ void zero_kernel(float* acc) {
    int i = blockIdx.x * 1024 + threadIdx.x;
    if (i < ACC_FLOATS) acc[i] = 0.0f;
}

// ---------------- CE + Dice fused ----------------
__global__ __launch_bounds__(256) void ce_dice_kernel(const float* __restrict__ logits,
                                                      const int* __restrict__ cls,
                                                      float* __restrict__ acc) {
    int b = blockIdx.y;
    int tid = threadIdx.x;
    int vb = (blockIdx.x * 256 + tid) * 4;
    const float* lg = logits + (size_t)b * 8 * DHW;
    const int* cl = cls + (size_t)b * DHW;

    float4 xc[8];
#pragma unroll
    for (int c = 0; c < 8; ++c)
        xc[c] = *reinterpret_cast<const float4*>(&lg[(size_t)c * DHW + vb]);
    int4 t4 = *reinterpret_cast<const int4*>(&cl[vb]);
    int tt[4] = {t4.x, t4.y, t4.z, t4.w};

    float nll = 0.f, cardp[8], inter[8], cardg[8];
#pragma unroll
    for (int c = 0; c < 8; ++c) { cardp[c] = 0.f; inter[c] = 0.f; cardg[c] = 0.f; }

#pragma unroll
    for (int j = 0; j < 4; ++j) {
        float x[8];
#pragma unroll
        for (int c = 0; c < 8; ++c) x[c] = ((const float*)&xc[c])[j];
        int t = tt[j];
        bool valid = (t != -100);
        float mx = x[0];
#pragma unroll
        for (int c = 1; c < 8; ++c) mx = fmaxf(mx, x[c]);
        float e[8], s = 0.f;
#pragma unroll
        for (int c = 0; c < 8; ++c) { e[c] = __expf(x[c] - mx); s += e[c]; }
        float inv = 1.0f / s;
        float lse = __logf(s);
        if (valid) {
#pragma unroll
            for (int c = 0; c < 8; ++c) {
                float p = e[c] * inv;
                cardp[c] += p;
                if (t == c) { inter[c] += p; cardg[c] += 1.f; nll += mx + lse - x[c]; }
            }
        }
    }

    __shared__ float sh[25];
    if (tid < 25) sh[tid] = 0.f;
    __syncthreads();
    int lane = tid & 63;
    float vals[25];
    vals[0] = nll;
#pragma unroll
    for (int c = 0; c < 8; ++c) { vals[1 + c] = cardp[c]; vals[9 + c] = inter[c]; vals[17 + c] = cardg[c]; }
#pragma unroll
    for (int i = 0; i < 25; ++i) {
        float r = vals[i];
#pragma unroll
        for (int off = 32; off > 0; off >>= 1) r += __shfl_down(r, off, 64);
        if (lane == 0) atomicAdd(&sh[i], r);
    }
    __syncthreads();
    if (tid < 25) {
        int dst;
        if (tid == 0) dst = OFF_NLL;
        else if (tid < 9) dst = OFF_CARDP + b * 8 + (tid - 1);
        else if (tid < 17) dst = OFF_INTER + b * 8 + (tid - 9);
        else dst = OFF_CARDG + b * 8 + (tid - 17);
        atomicAdd(&acc[dst], sh[tid]);
    }
}

// ---------------- boundary mask precompute (u8 per voxel) ----------------
__global__ __launch_bounds__(256) void boundary_kernel(const int* __restrict__ labels,
                                                       unsigned char* __restrict__ bnd) {
    int b = blockIdx.y;
    int vb = (blockIdx.x * 256 + threadIdx.x) * 4;
    const int* L = labels + (size_t)b * DHW;
    int x = vb & 127, y = (vb >> 7) & 127, z = vb >> 14;
    int4 c = *reinterpret_cast<const int4*>(&L[vb]);
    int z0 = max(z - 1, 0), z1 = min(z + 1, 63);
    int y0 = max(y - 1, 0), y1 = min(y + 1, 127);
    int xm = max(x - 1, 0), xp = min(x + 4, 127);
    unsigned b0 = 0, b1 = 0, b2 = 0, b3 = 0;
    for (int zz = z0; zz <= z1; ++zz)
        for (int yy = y0; yy <= y1; ++yy) {
            const int* row = L + (zz << 14) + (yy << 7);
            int4 r = *reinterpret_cast<const int4*>(&row[x]);
            int rm = row[xm], rp = row[xp];
            b0 |= (rm != c.x) | (r.x != c.x) | (r.y != c.x);
            b1 |= (r.x != c.y) | (r.y != c.y) | (r.z != c.y);
            b2 |= (r.y != c.z) | (r.z != c.z) | (r.w != c.z);
            b3 |= (r.z != c.w) | (r.w != c.w) | (rp != c.w);
        }
    unsigned pack = b0 | (b1 << 8) | (b2 << 16) | (b3 << 24);
    *reinterpret_cast<unsigned*>(&bnd[(size_t)b * DHW + vb]) = pack;
}

// ---------------- pass 1: segment sums via MFMA ----------------
// cnum[k,c] = sum_v w_v*[l_v==k]*e[c,v]  as 16x16x32 bf16 MFMA over 32-voxel chunks.
// wsum[k] = A . ones-col ; cnt[k] = onehot . ones-col  (two extra MFMAs).
__global__ __launch_bounds__(256) void segsum_kernel(const float* __restrict__ embed,
                                                     const int* __restrict__ labels,
                                                     const unsigned char* __restrict__ bnd,
                                                     float* __restrict__ acc) {
    int b = blockIdx.y;
    int tid = threadIdx.x;
    int lane = tid & 63;
    int wv = tid >> 6;
    int m = lane & 15;       // A-row (label m+1) / B-col (channel m)
    int quad = lane >> 4;    // K-slice selector

    const int* L = labels + (size_t)b * DHW;
    const float* E = embed + (size_t)b * 16 * DHW + (size_t)m * DHW;
    const unsigned char* Bd = bnd + (size_t)b * DHW;

    int waveId = blockIdx.x * 4 + wv;
    int base0 = waveId * 512;       // 16 iters x 32 voxels

    f32x4 acc_c = {0.f, 0.f, 0.f, 0.f};
    f32x4 acc_w = {0.f, 0.f, 0.f, 0.f};
    f32x4 acc_n = {0.f, 0.f, 0.f, 0.f};

    FragU ones_col;                 // B2: col 0 = 1.0, others 0
#pragma unroll
    for (int j = 0; j < 8; ++j) ones_col.s[j] = (m == 0) ? (short)0x3F80 : (short)0;

    for (int i = 0; i < 16; ++i) {
        int off = base0 + i * 32 + quad * 8;
        int4 l0 = *reinterpret_cast<const int4*>(&L[off]);
        int4 l1 = *reinterpret_cast<const int4*>(&L[off + 4]);
        unsigned bb0 = *reinterpret_cast<const unsigned*>(&Bd[off]);
        unsigned bb1 = *reinterpret_cast<const unsigned*>(&Bd[off + 4]);
        float4 f0 = *reinterpret_cast<const float4*>(&E[off]);
        float4 f1 = *reinterpret_cast<const float4*>(&E[off + 4]);

        int ls[8] = {l0.x, l0.y, l0.z, l0.w, l1.x, l1.y, l1.z, l1.w};
        float fs[8] = {f0.x, f0.y, f0.z, f0.w, f1.x, f1.y, f1.z, f1.w};

        FragU a, a2, bf;
#pragma unroll
        for (int j = 0; j < 8; ++j) {
            unsigned byte = ((j < 4 ? bb0 : bb1) >> ((j & 3) * 8)) & 0xFF;
            short w = byte ? (short)0x4120 : (short)0x3F80;   // 10.0 : 1.0
            bool hit = (ls[j] == m + 1);
            a.s[j]  = hit ? w : (short)0;
            a2.s[j] = hit ? (short)0x3F80 : (short)0;
            bf.s[j] = f2bf(fs[j]);
        }
        acc_c = __builtin_amdgcn_mfma_f32_16x16x32_bf16(a.v, bf.v, acc_c, 0, 0, 0);
        acc_w = __builtin_amdgcn_mfma_f32_16x16x32_bf16(a.v, ones_col.v, acc_w, 0, 0, 0);
        acc_n = __builtin_amdgcn_mfma_f32_16x16x32_bf16(a2.v, ones_col.v, acc_n, 0, 0, 0);
    }

    // block-level reduce: D row = quad*4 + reg, col = m
    __shared__ float cacc[288];     // 256 cnum + 16 wsum + 16 cnt
    for (int i = tid; i < 288; i += 256) cacc[i] = 0.f;
    __syncthreads();
#pragma unroll
    for (int r = 0; r < 4; ++r)
        atomicAdd(&cacc[(quad * 4 + r) * 16 + m], acc_c[r]);
    if (m == 0) {
#pragma unroll
        for (int r = 0; r < 4; ++r) {
            atomicAdd(&cacc[256 + quad * 4 + r], acc_w[r]);
            atomicAdd(&cacc[272 + quad * 4 + r], acc_n[r]);
        }
    }
    __syncthreads();
    {   // global accumulate
        int row = tid >> 4, col = tid & 15;   // all 256 threads
        atomicAdd(&acc[OFF_CNUM + (b * 17 + row + 1) * 16 + col], cacc[tid]);
        if (tid < 16) atomicAdd(&acc[OFF_WSUM + b * 17 + tid + 1], cacc[256 + tid]);
        else if (tid < 32) atomicAdd(&acc[OFF_CNT + b * 17 + (tid - 16) + 1], cacc[256 + tid]);
    }
}

__global__ void centers_kernel(float* acc) {
    int i = blockIdx.x * 256 + threadIdx.x;
    if (i < 544) {
        int bk = i >> 4;
        acc[OFF_CTR + i] = acc[OFF_CNUM + i] / (acc[OFF_WSUM + bk] + 1e-8f);
    }
}

// ---------------- pass 2: pull ----------------
__global__ __launch_bounds__(256) void pull_kernel(const float* __restrict__ embed,
                                                   const int* __restrict__ labels,
                                                   const unsigned char* __restrict__ bnd,
                                                   float* __restrict__ acc) {
    int b = blockIdx.y;
    int tid = threadIdx.x;
    int wv = tid >> 6;
    __shared__ float ctr[17 * 17];
    __shared__ float ps[4 * 20];    // per-wave privatized
    for (int i = tid; i < 17 * 17; i += 256) {
        int k = i / 17, c = i % 17;
        ctr[i] = (c < 16) ? acc[OFF_CTR + (b * 17 + k) * 16 + c] : 0.f;
    }
    for (int i = tid; i < 80; i += 256) ps[i] = 0.f;
    __syncthreads();

    const int* L = labels + (size_t)b * DHW;
    const float* E = embed + (size_t)b * 16 * DHW;
    const unsigned char* Bd = bnd + (size_t)b * DHW;
    int vb = (blockIdx.x * 256 + tid) * 4;

    int4 l4 = *reinterpret_cast<const int4*>(&L[vb]);
    int l[4] = {l4.x, l4.y, l4.z, l4.w};
    unsigned bb = *reinterpret_cast<const unsigned*>(&Bd[vb]);

    float4 e4[16];
#pragma unroll
    for (int c = 0; c < 16; ++c)
        e4[c] = *reinterpret_cast<const float4*>(&E[(size_t)c * DHW + vb]);

#pragma unroll
    for (int j = 0; j < 4; ++j) {
        if (l[j] != 0) {
            float w = ((bb >> (8 * j)) & 0xFF) ? 10.f : 1.f;
            const float* cg = &ctr[l[j] * 17];
            float d2 = 0.f;
#pragma unroll
            for (int c = 0; c < 16; ++c) {
                float dd = ((const float*)&e4[c])[j] - cg[c];
                d2 += dd * dd;
            }
            float d = fmaxf(sqrtf(d2) - 0.5f, 0.f);
            atomicAdd(&ps[wv * 20 + l[j]], d * d * w);
        }
    }
    __syncthreads();
    if (tid >= 1 && tid < 17) {
        float v = ps[tid] + ps[20 + tid] + ps[40 + tid] + ps[60 + tid];
        if (v != 0.f) atomicAdd(&acc[OFF_PULL + b * 17 + tid], v);
    }
}

// ---------------- finalize ----------------
__global__ void finalize_kernel(const float* __restrict__ acc, float* __restrict__ out) {
    __shared__ float sh_push[2], sh_norm[2], sh_pull[2], sh_npres[2];
    int tid = threadIdx.x;
    if (tid < 2) { sh_push[tid] = 0.f; sh_norm[tid] = 0.f; sh_pull[tid] = 0.f; sh_npres[tid] = 0.f; }
    __syncthreads();

    if (tid < 32) {
        int b = tid >> 4, k = (tid & 15) + 1;
        float cnt = acc[OFF_CNT + b * 17 + k];
        if (cnt > 0.f) {
            atomicAdd(&sh_npres[b], 1.f);
            atomicAdd(&sh_pull[b], acc[OFF_PULL + b * 17 + k] / fmaxf(cnt, 1.f));
            const float* c = &acc[OFF_CTR + (b * 17 + k) * 16];
            float n2 = 0.f;
            for (int i = 0; i < 16; ++i) n2 += c[i] * c[i];
            atomicAdd(&sh_norm[b], sqrtf(n2));
        }
    }
    for (int t = tid; t < 240; t += blockDim.x) {
        int b = t / 120, p = t % 120;
        int i = 1, rem = p;
        while (rem >= (16 - i)) { rem -= (16 - i); ++i; }
        int j = i + 1 + rem;
        bool pi = acc[OFF_CNT + b * 17 + i] > 0.f;
        bool pj = acc[OFF_CNT + b * 17 + j] > 0.f;
        if (pi && pj) {
            const float* ci = &acc[OFF_CTR + (b * 17 + i) * 16];
            const float* cj = &acc[OFF_CTR + (b * 17 + j) * 16];
            float d2 = 0.f;
            for (int c = 0; c < 16; ++c) { float dd = ci[c] - cj[c]; d2 += dd * dd; }
            float r = fmaxf(3.0f - sqrtf(d2), 0.f);
            atomicAdd(&sh_push[b], r * r);
        }
    }
    __syncthreads();
    if (tid == 0) {
        float nll = acc[OFF_NLL];
        float vcnt = 0.f;
        for (int i = 0; i < 16; ++i) vcnt += acc[OFF_CARDG + i];
        float ce = nll / fmaxf(vcnt, 1.f);
        float dsum = 0.f;
        for (int i = 0; i < 16; ++i) {
            float it = acc[OFF_INTER + i], cp = acc[OFF_CARDP + i], cg = acc[OFF_CARDG + i];
            dsum += (2.f * it + 1e-5f) / (cp + cg + 1e-5f);
        }
        float dice = 1.f - dsum / 16.f;
        float lp = 0.f, lpu = 0.f, ln = 0.f, val = 0.f;
        for (int b = 0; b < 2; ++b) {
            float npres = sh_npres[b];
            lp += sh_pull[b];
            float npairs = npres * (npres - 1.f) * 0.5f;
            lpu += (npairs > 0.f) ? sh_push[b] / fmaxf(npairs, 1.f) : 0.f;
            ln += (npres > 0.f) ? sh_norm[b] / fmaxf(npres, 1.f) : 0.f;
            val += (npres > 0.f) ? 1.f : 0.f;
        }
        float n = fmaxf(val, 1.f);
        float ins = (1.0f * lp + 1.0f * lpu + 0.001f * ln) / n;
        float sem = ce + dice;
        out[0] = sem + ins;
        out[1] = sem;
        out[2] = ce;
        out[3] = dice;
        out[4] = ins;
    }
}

extern "C" void kernel_launch(void* const* d_in, const int* in_sizes, int n_in,
                              void* d_out, int out_size, void* d_ws, size_t ws_size,
                              hipStream_t stream) {
    const float* sem = (const float*)d_in[0];
    const float* emb = (const float*)d_in[1];
    const int* cls = (const int*)d_in[2];
    const int* lab = (const int*)d_in[3];
    float* out = (float*)d_out;
    float* acc = (float*)d_ws;
    unsigned char* bnd = (unsigned char*)d_ws + BND_BYTE_OFF;

    hipLaunchKernelGGL(zero_kernel, dim3(2), dim3(1024), 0, stream, acc);
    hipLaunchKernelGGL(ce_dice_kernel, dim3(1024, 2), dim3(256), 0, stream, sem, cls, acc);
    hipLaunchKernelGGL(boundary_kernel, dim3(1024, 2), dim3(256), 0, stream, lab, bnd);
    hipLaunchKernelGGL(segsum_kernel, dim3(512, 2), dim3(256), 0, stream, emb, lab, bnd, acc);
    hipLaunchKernelGGL(centers_kernel, dim3(3), dim3(256), 0, stream, acc);
    hipLaunchKernelGGL(pull_kernel, dim3(1024, 2), dim3(256), 0, stream, emb, lab, bnd, acc);
    hipLaunchKernelGGL(finalize_kernel, dim3(1), dim3(256), 0, stream, acc, out);
}

// Round 3
// 335.808 us; speedup vs baseline: 1.5844x; 1.1703x over previous
//
#include <hip/hip_runtime.h>

#define DHW (64*128*128)
#define MIR 32

// accumulator layout in d_ws (floats)
#define OFF_CEM   0        // [MIR][49]: nll, cardp[2][8], inter[2][8], cardg[2][8]
#define OFF_SEGM  1568     // [MIR][2][306]: cnum[17][16] (slots 16..271), wsum[17] (272..288), cnt[17] (289..305)
#define OFF_PULLM 21152    // [MIR][2][17]
#define OFF_CTR   22240    // [2][17][16]
#define OFF_CNT   22784    // [2][17]
#define ACC_FLOATS 22818
#define BND_BYTE_OFF (128*1024)

typedef __bf16 bf16x8 __attribute__((ext_vector_type(8)));
typedef float f32x4 __attribute__((ext_vector_type(4)));
union FragU { short s[8]; bf16x8 v; };

__device__ inline short f2bf(float f) {   // RTNE float->bf16
    union { float f; unsigned u; } v; v.f = f;
    unsigned r = v.u + 0x7FFF + ((v.u >> 16) & 1);
    return (short)(r >> 16);
}

__global__ void zero_kernel(float* acc) {
    int i = blockIdx.x * 1024 + threadIdx.x;
    if (i < ACC_FLOATS) acc[i] = 0.0f;
}

// ---------------- CE + Dice fused ----------------
__global__ __launch_bounds__(256) void ce_dice_kernel(const float* __restrict__ logits,
                                                      const int* __restrict__ cls,
                                                      float* __restrict__ acc) {
    int b = blockIdx.y;
    int tid = threadIdx.x;
    int vb = (blockIdx.x * 256 + tid) * 4;
    const float* lg = logits + (size_t)b * 8 * DHW;
    const int* cl = cls + (size_t)b * DHW;

    float4 xc[8];
#pragma unroll
    for (int c = 0; c < 8; ++c)
        xc[c] = *reinterpret_cast<const float4*>(&lg[(size_t)c * DHW + vb]);
    int4 t4 = *reinterpret_cast<const int4*>(&cl[vb]);
    int tt[4] = {t4.x, t4.y, t4.z, t4.w};

    float nll = 0.f, cardp[8], inter[8], cardg[8];
#pragma unroll
    for (int c = 0; c < 8; ++c) { cardp[c] = 0.f; inter[c] = 0.f; cardg[c] = 0.f; }

#pragma unroll
    for (int j = 0; j < 4; ++j) {
        float x[8];
#pragma unroll
        for (int c = 0; c < 8; ++c) x[c] = ((const float*)&xc[c])[j];
        int t = tt[j];
        bool valid = (t != -100);
        float mx = x[0];
#pragma unroll
        for (int c = 1; c < 8; ++c) mx = fmaxf(mx, x[c]);
        float e[8], s = 0.f;
#pragma unroll
        for (int c = 0; c < 8; ++c) { e[c] = __expf(x[c] - mx); s += e[c]; }
        float inv = 1.0f / s;
        float lse = __logf(s);
        if (valid) {
#pragma unroll
            for (int c = 0; c < 8; ++c) {
                float p = e[c] * inv;
                cardp[c] += p;
                if (t == c) { inter[c] += p; cardg[c] += 1.f; nll += mx + lse - x[c]; }
            }
        }
    }

    __shared__ float sh[25];
    if (tid < 25) sh[tid] = 0.f;
    __syncthreads();
    int lane = tid & 63;
    float vals[25];
    vals[0] = nll;
#pragma unroll
    for (int c = 0; c < 8; ++c) { vals[1 + c] = cardp[c]; vals[9 + c] = inter[c]; vals[17 + c] = cardg[c]; }
#pragma unroll
    for (int i = 0; i < 25; ++i) {
        float r = vals[i];
#pragma unroll
        for (int off = 32; off > 0; off >>= 1) r += __shfl_down(r, off, 64);
        if (lane == 0) atomicAdd(&sh[i], r);
    }
    __syncthreads();
    if (tid < 25) {
        int mir = blockIdx.x & (MIR - 1);
        int dst;
        if (tid == 0) dst = 0;
        else if (tid < 9) dst = 1 + b * 8 + (tid - 1);
        else if (tid < 17) dst = 17 + b * 8 + (tid - 9);
        else dst = 33 + b * 8 + (tid - 17);
        atomicAdd(&acc[OFF_CEM + mir * 49 + dst], sh[tid]);
    }
}

// ---------------- boundary mask (u8/voxel) with early exit ----------------
__global__ __launch_bounds__(256) void boundary_kernel(const int* __restrict__ labels,
                                                       unsigned char* __restrict__ bnd) {
    int b = blockIdx.y;
    int vb = (blockIdx.x * 256 + threadIdx.x) * 4;
    const int* L = labels + (size_t)b * DHW;
    int x = vb & 127, y = (vb >> 7) & 127, z = vb >> 14;
    int4 c = *reinterpret_cast<const int4*>(&L[vb]);
    int z0 = max(z - 1, 0), z1 = min(z + 1, 63);
    int y0 = max(y - 1, 0), y1 = min(y + 1, 127);
    int xm = max(x - 1, 0), xp = min(x + 4, 127);
    unsigned b0 = 0, b1 = 0, b2 = 0, b3 = 0;
    for (int zz = z0; zz <= z1; ++zz) {
        for (int yy = y0; yy <= y1; ++yy) {
            const int* row = L + (zz << 14) + (yy << 7);
            int4 r = *reinterpret_cast<const int4*>(&row[x]);
            int rm = row[xm], rp = row[xp];
            b0 |= (rm != c.x) | (r.x != c.x) | (r.y != c.x);
            b1 |= (r.x != c.y) | (r.y != c.y) | (r.z != c.y);
            b2 |= (r.y != c.z) | (r.z != c.z) | (r.w != c.z);
            b3 |= (r.z != c.w) | (r.w != c.w) | (rp != c.w);
            if (b0 & b1 & b2 & b3) goto done;
        }
    }
done:
    unsigned pack = b0 | (b1 << 8) | (b2 << 16) | (b3 << 24);
    *reinterpret_cast<unsigned*>(&bnd[(size_t)b * DHW + vb]) = pack;
}

// ---------------- pass 1: segment sums via MFMA, prefetch depth 2 ----------------
__global__ __launch_bounds__(256) void segsum_kernel(const float* __restrict__ embed,
                                                     const int* __restrict__ labels,
                                                     const unsigned char* __restrict__ bnd,
                                                     float* __restrict__ acc) {
    int b = blockIdx.y;
    int tid = threadIdx.x;
    int lane = tid & 63;
    int wv = tid >> 6;
    int m = lane & 15;       // A-row (label m+1) / B-col (channel m)
    int quad = lane >> 4;    // K-slice selector

    const int* L = labels + (size_t)b * DHW;
    const float* E = embed + (size_t)b * 16 * DHW + (size_t)m * DHW;
    const unsigned char* Bd = bnd + (size_t)b * DHW;

    int waveId = blockIdx.x * 4 + wv;
    int off = waveId * 256 + quad * 8;   // 8 iters x 32 voxels per wave

    f32x4 acc_c = {0.f, 0.f, 0.f, 0.f};
    f32x4 acc_w = {0.f, 0.f, 0.f, 0.f};
    f32x4 acc_n = {0.f, 0.f, 0.f, 0.f};

    FragU ones_col;
#pragma unroll
    for (int j = 0; j < 8; ++j) ones_col.s[j] = (m == 0) ? (short)0x3F80 : (short)0;

    int4 l0 = *reinterpret_cast<const int4*>(&L[off]);
    int4 l1 = *reinterpret_cast<const int4*>(&L[off + 4]);
    unsigned bb0 = *reinterpret_cast<const unsigned*>(&Bd[off]);
    unsigned bb1 = *reinterpret_cast<const unsigned*>(&Bd[off + 4]);
    float4 f0 = *reinterpret_cast<const float4*>(&E[off]);
    float4 f1 = *reinterpret_cast<const float4*>(&E[off + 4]);

    for (int i = 0; i < 8; ++i) {
        int4 nl0, nl1; unsigned nb0, nb1; float4 nf0, nf1;
        if (i < 7) {
            int noff = off + 32;
            nl0 = *reinterpret_cast<const int4*>(&L[noff]);
            nl1 = *reinterpret_cast<const int4*>(&L[noff + 4]);
            nb0 = *reinterpret_cast<const unsigned*>(&Bd[noff]);
            nb1 = *reinterpret_cast<const unsigned*>(&Bd[noff + 4]);
            nf0 = *reinterpret_cast<const float4*>(&E[noff]);
            nf1 = *reinterpret_cast<const float4*>(&E[noff + 4]);
        }

        int ls[8] = {l0.x, l0.y, l0.z, l0.w, l1.x, l1.y, l1.z, l1.w};
        float fs[8] = {f0.x, f0.y, f0.z, f0.w, f1.x, f1.y, f1.z, f1.w};

        FragU a, a2, bf;
#pragma unroll
        for (int j = 0; j < 8; ++j) {
            unsigned byte = ((j < 4 ? bb0 : bb1) >> ((j & 3) * 8)) & 0xFF;
            short w = byte ? (short)0x4120 : (short)0x3F80;   // 10.0 : 1.0
            bool hit = (ls[j] == m + 1);
            a.s[j]  = hit ? w : (short)0;
            a2.s[j] = hit ? (short)0x3F80 : (short)0;
            bf.s[j] = f2bf(fs[j]);
        }
        acc_c = __builtin_amdgcn_mfma_f32_16x16x32_bf16(a.v, bf.v, acc_c, 0, 0, 0);
        acc_w = __builtin_amdgcn_mfma_f32_16x16x32_bf16(a.v, ones_col.v, acc_w, 0, 0, 0);
        acc_n = __builtin_amdgcn_mfma_f32_16x16x32_bf16(a2.v, ones_col.v, acc_n, 0, 0, 0);

        l0 = nl0; l1 = nl1; bb0 = nb0; bb1 = nb1; f0 = nf0; f1 = nf1;
        off += 32;
    }

    // block-level reduce: D row = quad*4 + reg (segment-1), col = m (channel)
    __shared__ float cacc[288];
    for (int i = tid; i < 288; i += 256) cacc[i] = 0.f;
    __syncthreads();
#pragma unroll
    for (int r = 0; r < 4; ++r)
        atomicAdd(&cacc[(quad * 4 + r) * 16 + m], acc_c[r]);
    if (m == 0) {
#pragma unroll
        for (int r = 0; r < 4; ++r) {
            atomicAdd(&cacc[256 + quad * 4 + r], acc_w[r]);
            atomicAdd(&cacc[272 + quad * 4 + r], acc_n[r]);
        }
    }
    __syncthreads();
    {
        int mir = blockIdx.x & (MIR - 1);
        float* segbase = acc + OFF_SEGM + mir * 612 + b * 306;
        atomicAdd(&segbase[16 + tid], cacc[tid]);          // cnum slot k*16+c, k=row+1
        if (tid < 16) atomicAdd(&segbase[272 + 1 + tid], cacc[256 + tid]);          // wsum
        else if (tid < 32) atomicAdd(&segbase[289 + 1 + (tid - 16)], cacc[256 + tid]);  // cnt
    }
}

// ---------------- centers: sum mirrors, divide ----------------
__global__ __launch_bounds__(1024) void centers_kernel(float* acc) {
    int tid = threadIdx.x;
    if (tid < 544) {
        int b = tid / 272, r = tid % 272;       // r = k*16+c
        int k = r >> 4;
        float cn = 0.f, ws = 0.f;
        for (int mv = 0; mv < MIR; ++mv) {
            const float* segbase = acc + OFF_SEGM + mv * 612 + b * 306;
            if (r >= 16) cn += segbase[r];
            ws += segbase[272 + k];
        }
        acc[OFF_CTR + tid] = (r >= 16) ? cn / (ws + 1e-8f) : 0.f;
    } else if (tid < 578) {
        int j = tid - 544;                       // b*17+k
        int b = j / 17, k = j % 17;
        float s = 0.f;
        for (int mv = 0; mv < MIR; ++mv)
            s += acc[OFF_SEGM + mv * 612 + b * 306 + 289 + k];
        acc[OFF_CNT + j] = s;
    }
}

// ---------------- pass 2: pull ----------------
__global__ __launch_bounds__(256) void pull_kernel(const float* __restrict__ embed,
                                                   const int* __restrict__ labels,
                                                   const unsigned char* __restrict__ bnd,
                                                   float* __restrict__ acc) {
    int b = blockIdx.y;
    int tid = threadIdx.x;
    int wv = tid >> 6;
    __shared__ float ctr[17 * 16];   // contiguous rows -> ds_read_b128, same-label broadcast
    __shared__ float ps[4 * 20];
    for (int i = tid; i < 272; i += 256) ctr[i] = acc[OFF_CTR + b * 272 + i];
    for (int i = tid; i < 80; i += 256) ps[i] = 0.f;
    __syncthreads();

    const int* L = labels + (size_t)b * DHW;
    const float* E = embed + (size_t)b * 16 * DHW;
    const unsigned char* Bd = bnd + (size_t)b * DHW;
    int vb = (blockIdx.x * 256 + tid) * 4;

    int4 l4 = *reinterpret_cast<const int4*>(&L[vb]);
    int l[4] = {l4.x, l4.y, l4.z, l4.w};
    unsigned bb = *reinterpret_cast<const unsigned*>(&Bd[vb]);

    float4 e4[16];
#pragma unroll
    for (int c = 0; c < 16; ++c)
        e4[c] = *reinterpret_cast<const float4*>(&E[(size_t)c * DHW + vb]);

#pragma unroll
    for (int j = 0; j < 4; ++j) {
        if (l[j] != 0) {
            float w = ((bb >> (8 * j)) & 0xFF) ? 10.f : 1.f;
            const float4* cg = reinterpret_cast<const float4*>(&ctr[l[j] * 16]);
            float d2 = 0.f;
#pragma unroll
            for (int q = 0; q < 4; ++q) {
                float4 cv = cg[q];
                float d0 = ((const float*)&e4[4 * q + 0])[j] - cv.x;
                float d1 = ((const float*)&e4[4 * q + 1])[j] - cv.y;
                float dd2 = ((const float*)&e4[4 * q + 2])[j] - cv.z;
                float d3 = ((const float*)&e4[4 * q + 3])[j] - cv.w;
                d2 += d0 * d0 + d1 * d1 + dd2 * dd2 + d3 * d3;
            }
            float d = fmaxf(sqrtf(d2) - 0.5f, 0.f);
            atomicAdd(&ps[wv * 20 + l[j]], d * d * w);
        }
    }
    __syncthreads();
    if (tid >= 1 && tid < 17) {
        float v = ps[tid] + ps[20 + tid] + ps[40 + tid] + ps[60 + tid];
        int mir = blockIdx.x & (MIR - 1);
        if (v != 0.f) atomicAdd(&acc[OFF_PULLM + mir * 34 + b * 17 + tid], v);
    }
}

// ---------------- finalize ----------------
__global__ __launch_bounds__(256) void finalize_kernel(const float* __restrict__ acc, float* __restrict__ out) {
    __shared__ float s_ce[49], s_pl[34];
    __shared__ float sh_push[2], sh_norm[2], sh_pull[2], sh_npres[2];
    int tid = threadIdx.x;
    if (tid < 49) {
        float s = 0.f;
        for (int mv = 0; mv < MIR; ++mv) s += acc[OFF_CEM + mv * 49 + tid];
        s_ce[tid] = s;
    }
    if (tid >= 64 && tid < 98) {
        int j = tid - 64;
        float s = 0.f;
        for (int mv = 0; mv < MIR; ++mv) s += acc[OFF_PULLM + mv * 34 + j];
        s_pl[j] = s;
    }
    if (tid < 2) { sh_push[tid] = 0.f; sh_norm[tid] = 0.f; sh_pull[tid] = 0.f; sh_npres[tid] = 0.f; }
    __syncthreads();

    if (tid < 32) {
        int b = tid >> 4, k = (tid & 15) + 1;
        float cnt = acc[OFF_CNT + b * 17 + k];
        if (cnt > 0.f) {
            atomicAdd(&sh_npres[b], 1.f);
            atomicAdd(&sh_pull[b], s_pl[b * 17 + k] / fmaxf(cnt, 1.f));
            const float* c = &acc[OFF_CTR + (b * 17 + k) * 16];
            float n2 = 0.f;
            for (int i = 0; i < 16; ++i) n2 += c[i] * c[i];
            atomicAdd(&sh_norm[b], sqrtf(n2));
        }
    }
    for (int t = tid; t < 240; t += blockDim.x) {
        int b = t / 120, p = t % 120;
        int i = 1, rem = p;
        while (rem >= (16 - i)) { rem -= (16 - i); ++i; }
        int j = i + 1 + rem;
        bool pi = acc[OFF_CNT + b * 17 + i] > 0.f;
        bool pj = acc[OFF_CNT + b * 17 + j] > 0.f;
        if (pi && pj) {
            const float* ci = &acc[OFF_CTR + (b * 17 + i) * 16];
            const float* cj = &acc[OFF_CTR + (b * 17 + j) * 16];
            float d2 = 0.f;
            for (int c = 0; c < 16; ++c) { float dd = ci[c] - cj[c]; d2 += dd * dd; }
            float r = fmaxf(3.0f - sqrtf(d2), 0.f);
            atomicAdd(&sh_push[b], r * r);
        }
    }
    __syncthreads();
    if (tid == 0) {
        float nll = s_ce[0];
        float vcnt = 0.f;
        for (int i = 0; i < 16; ++i) vcnt += s_ce[33 + i];
        float ce = nll / fmaxf(vcnt, 1.f);
        float dsum = 0.f;
        for (int i = 0; i < 16; ++i) {
            float it = s_ce[17 + i], cp = s_ce[1 + i], cg = s_ce[33 + i];
            dsum += (2.f * it + 1e-5f) / (cp + cg + 1e-5f);
        }
        float dice = 1.f - dsum / 16.f;
        float lp = 0.f, lpu = 0.f, ln = 0.f, val = 0.f;
        for (int b = 0; b < 2; ++b) {
            float npres = sh_npres[b];
            lp += sh_pull[b];
            float npairs = npres * (npres - 1.f) * 0.5f;
            lpu += (npairs > 0.f) ? sh_push[b] / fmaxf(npairs, 1.f) : 0.f;
            ln += (npres > 0.f) ? sh_norm[b] / fmaxf(npres, 1.f) : 0.f;
            val += (npres > 0.f) ? 1.f : 0.f;
        }
        float n = fmaxf(val, 1.f);
        float ins = (1.0f * lp + 1.0f * lpu + 0.001f * ln) / n;
        float sem = ce + dice;
        out[0] = sem + ins;
        out[1] = sem;
        out[2] = ce;
        out[3] = dice;
        out[4] = ins;
    }
}

extern "C" void kernel_launch(void* const* d_in, const int* in_sizes, int n_in,
                              void* d_out, int out_size, void* d_ws, size_t ws_size,
                              hipStream_t stream) {
    const float* sem = (const float*)d_in[0];
    const float* emb = (const float*)d_in[1];
    const int* cls = (const int*)d_in[2];
    const int* lab = (const int*)d_in[3];
    float* out = (float*)d_out;
    float* acc = (float*)d_ws;
    unsigned char* bnd = (unsigned char*)d_ws + BND_BYTE_OFF;

    hipLaunchKernelGGL(zero_kernel, dim3(23), dim3(1024), 0, stream, acc);
    hipLaunchKernelGGL(ce_dice_kernel, dim3(1024, 2), dim3(256), 0, stream, sem, cls, acc);
    hipLaunchKernelGGL(boundary_kernel, dim3(1024, 2), dim3(256), 0, stream, lab, bnd);
    hipLaunchKernelGGL(segsum_kernel, dim3(1024, 2), dim3(256), 0, stream, emb, lab, bnd, acc);
    hipLaunchKernelGGL(centers_kernel, dim3(1), dim3(1024), 0, stream, acc);
    hipLaunchKernelGGL(pull_kernel, dim3(1024, 2), dim3(256), 0, stream, emb, lab, bnd, acc);
    hipLaunchKernelGGL(finalize_kernel, dim3(1), dim3(256), 0, stream, acc, out);
}